// Round 1
// baseline (26250.308 us; speedup 1.0000x reference)
//
#include <hip/hip_runtime.h>
#include <math.h>

#define HD 512   // hidden size H
#define TT 512   // sequence length T
#define NB 128   // batch B
#define G3 1536  // 3*H

// Tiled transpose: A (rows x cols) -> At (cols x rows)
__global__ __launch_bounds__(256) void transpose_tiled(const float* __restrict__ A,
                                                       float* __restrict__ At,
                                                       int rows, int cols) {
    __shared__ float tile[32][33];
    int bx = blockIdx.x * 32;  // col base in A
    int by = blockIdx.y * 32;  // row base in A
    int tx = threadIdx.x, ty = threadIdx.y;  // 32 x 8
    #pragma unroll
    for (int i = 0; i < 32; i += 8)
        tile[ty + i][tx] = A[(by + ty + i) * cols + (bx + tx)];
    __syncthreads();
    #pragma unroll
    for (int i = 0; i < 32; i += 8)
        At[(bx + ty + i) * rows + (by + tx)] = tile[tx][ty + i];
}

__device__ __forceinline__ float sigm(float v) {
    return 1.0f / (1.0f + __expf(-v));
}

// 2 batches per block, 1024 threads = (k-half kg) x (hidden unit t).
// Each weight load feeds 2 FMAs (batch reuse); k-dim split across 2 thread
// groups doubles waves/SIMD (2 -> 4) for latency hiding.
// WhT layout: WhT[k*1536 + j] = Wh[j*512 + k]
#define GATE_DOT(WT)                                                            \
    float ar0=0.f, az0=0.f, an0=0.f, ar1=0.f, az1=0.f, an1=0.f;                 \
    {                                                                           \
        const float* wp = (WT) + t + (size_t)kbase * G3;                        \
        _Pragma("unroll 2")                                                     \
        for (int k = 0; k < 256; k += 4) {                                      \
            const float4 h0 = *(const float4*)&h_s[0][kbase + k];               \
            const float4 h1 = *(const float4*)&h_s[1][kbase + k];               \
            const float* w = wp + (size_t)k * G3;                               \
            float wr, wz, wn;                                                   \
            wr=w[0]; wz=w[HD]; wn=w[2*HD];                                      \
            ar0=fmaf(wr,h0.x,ar0); az0=fmaf(wz,h0.x,az0); an0=fmaf(wn,h0.x,an0);\
            ar1=fmaf(wr,h1.x,ar1); az1=fmaf(wz,h1.x,az1); an1=fmaf(wn,h1.x,an1);\
            wr=w[G3]; wz=w[G3+HD]; wn=w[G3+2*HD];                               \
            ar0=fmaf(wr,h0.y,ar0); az0=fmaf(wz,h0.y,az0); an0=fmaf(wn,h0.y,an0);\
            ar1=fmaf(wr,h1.y,ar1); az1=fmaf(wz,h1.y,az1); an1=fmaf(wn,h1.y,an1);\
            wr=w[2*G3]; wz=w[2*G3+HD]; wn=w[2*G3+2*HD];                         \
            ar0=fmaf(wr,h0.z,ar0); az0=fmaf(wz,h0.z,az0); an0=fmaf(wn,h0.z,an0);\
            ar1=fmaf(wr,h1.z,ar1); az1=fmaf(wz,h1.z,az1); an1=fmaf(wn,h1.z,an1);\
            wr=w[3*G3]; wz=w[3*G3+HD]; wn=w[3*G3+2*HD];                         \
            ar0=fmaf(wr,h0.w,ar0); az0=fmaf(wz,h0.w,az0); an0=fmaf(wn,h0.w,an0);\
            ar1=fmaf(wr,h1.w,ar1); az1=fmaf(wz,h1.w,az1); an1=fmaf(wn,h1.w,an1);\
        }                                                                       \
    }

__global__ __launch_bounds__(1024, 4) void gru_ae2(
    const float* __restrict__ x,
    const float* __restrict__ eWi, const float* __restrict__ ebi, const float* __restrict__ ebh,
    const float* __restrict__ dWi, const float* __restrict__ dbi, const float* __restrict__ dbh,
    const float* __restrict__ linW, const float* __restrict__ linb,
    const float* __restrict__ eWhT, const float* __restrict__ dWhT,
    float* __restrict__ out)
{
    const int b0  = blockIdx.x * 2;
    const int b1  = b0 + 1;
    const int tid = threadIdx.x;
    const int t   = tid & (HD - 1);   // hidden unit
    const int kg  = tid >> 9;         // k-half: 0 or 1
    const int kbase = kg << 8;        // 0 or 256

    __shared__ float h_s[2][HD];      // h for 2 batches
    __shared__ float x_s[2][TT];      // staged input rows
    __shared__ float red[6][HD];      // kg1 partial gate sums
    __shared__ float red_s[16];
    __shared__ float y_sh[2];

    h_s[kg][t] = 0.0f;
    if (kg == 0) x_s[0][t] = x[b0 * TT + t];
    else         x_s[1][t] = x[b1 * TT + t];

    const float lw = linW[t];
    const float lb = linb[0];

    // encoder per-unit params (used by kg==0 finish phase)
    float wi_r = eWi[t], wi_z = eWi[HD + t], wi_n = eWi[2 * HD + t];
    float c_r  = ebi[t] + ebh[t];
    float c_z  = ebi[HD + t] + ebh[HD + t];
    float bi_n = ebi[2 * HD + t], bh_n = ebh[2 * HD + t];
    __syncthreads();

    // ---------------- encoder ----------------
    for (int step = 0; step < TT; ++step) {
        GATE_DOT(eWhT)
        if (kg == 1) {
            red[0][t] = ar0; red[1][t] = az0; red[2][t] = an0;
            red[3][t] = ar1; red[4][t] = az1; red[5][t] = an1;
        }
        __syncthreads();
        if (kg == 0) {
            const float xr0 = x_s[0][step], xr1 = x_s[1][step];
            const float Ar0 = ar0 + red[0][t], Az0 = az0 + red[1][t], An0 = an0 + red[2][t];
            const float Ar1 = ar1 + red[3][t], Az1 = az1 + red[4][t], An1 = an1 + red[5][t];
            float r0 = sigm(fmaf(xr0, wi_r, c_r) + Ar0);
            float z0 = sigm(fmaf(xr0, wi_z, c_z) + Az0);
            float n0 = tanhf(fmaf(xr0, wi_n, bi_n) + r0 * (An0 + bh_n));
            h_s[0][t] = fmaf(z0, h_s[0][t] - n0, n0);
            float r1 = sigm(fmaf(xr1, wi_r, c_r) + Ar1);
            float z1 = sigm(fmaf(xr1, wi_z, c_z) + Az1);
            float n1 = tanhf(fmaf(xr1, wi_n, bi_n) + r1 * (An1 + bh_n));
            h_s[1][t] = fmaf(z1, h_s[1][t] - n1, n1);
        }
        __syncthreads();
    }

    // switch to decoder params
    wi_r = dWi[t]; wi_z = dWi[HD + t]; wi_n = dWi[2 * HD + t];
    c_r  = dbi[t] + dbh[t];
    c_z  = dbi[HD + t] + dbh[HD + t];
    bi_n = dbi[2 * HD + t]; bh_n = dbh[2 * HD + t];

    // y = h @ linW^T + lb  for both batches (waves 0-7 -> b0, 8-15 -> b1)
    {
        float p = h_s[kg][t] * lw;
        #pragma unroll
        for (int o = 32; o >= 1; o >>= 1) p += __shfl_down(p, o);
        if ((tid & 63) == 0) red_s[tid >> 6] = p;
        __syncthreads();
        if (tid == 0)   { float s = lb; for (int i = 0; i < 8;  ++i) s += red_s[i]; y_sh[0] = s; }
        if (tid == 512) { float s = lb; for (int i = 8; i < 16; ++i) s += red_s[i]; y_sh[1] = s; }
        __syncthreads();
    }

    // ---------------- decoder ----------------
    for (int step = 0; step < TT; ++step) {
        GATE_DOT(dWhT)
        if (kg == 1) {
            red[0][t] = ar0; red[1][t] = az0; red[2][t] = an0;
            red[3][t] = ar1; red[4][t] = az1; red[5][t] = an1;
        }
        __syncthreads();
        if (kg == 0) {
            const float y0 = y_sh[0], y1 = y_sh[1];
            const float Ar0 = ar0 + red[0][t], Az0 = az0 + red[1][t], An0 = an0 + red[2][t];
            const float Ar1 = ar1 + red[3][t], Az1 = az1 + red[4][t], An1 = an1 + red[5][t];
            float r0 = sigm(fmaf(y0, wi_r, c_r) + Ar0);
            float z0 = sigm(fmaf(y0, wi_z, c_z) + Az0);
            float n0 = tanhf(fmaf(y0, wi_n, bi_n) + r0 * (An0 + bh_n));
            h_s[0][t] = fmaf(z0, h_s[0][t] - n0, n0);
            float r1 = sigm(fmaf(y1, wi_r, c_r) + Ar1);
            float z1 = sigm(fmaf(y1, wi_z, c_z) + Az1);
            float n1 = tanhf(fmaf(y1, wi_n, bi_n) + r1 * (An1 + bh_n));
            h_s[1][t] = fmaf(z1, h_s[1][t] - n1, n1);
        }
        __syncthreads();

        // y = h @ linW^T + lb ; emit flipped
        float p = h_s[kg][t] * lw;
        #pragma unroll
        for (int o = 32; o >= 1; o >>= 1) p += __shfl_down(p, o);
        if ((tid & 63) == 0) red_s[tid >> 6] = p;
        __syncthreads();
        if (tid == 0) {
            float s = lb;
            #pragma unroll
            for (int i = 0; i < 8; ++i) s += red_s[i];
            y_sh[0] = s;
            out[b0 * TT + (TT - 1 - step)] = s;
        }
        if (tid == 512) {
            float s = lb;
            #pragma unroll
            for (int i = 8; i < 16; ++i) s += red_s[i];
            y_sh[1] = s;
            out[b1 * TT + (TT - 1 - step)] = s;
        }
        __syncthreads();
    }
}

extern "C" void kernel_launch(void* const* d_in, const int* in_sizes, int n_in,
                              void* d_out, int out_size, void* d_ws, size_t ws_size,
                              hipStream_t stream) {
    const float* x    = (const float*)d_in[0];
    const float* eWi  = (const float*)d_in[1];
    const float* eWh  = (const float*)d_in[2];
    const float* ebi  = (const float*)d_in[3];
    const float* ebh  = (const float*)d_in[4];
    const float* dWi  = (const float*)d_in[5];
    const float* dWh  = (const float*)d_in[6];
    const float* dbi  = (const float*)d_in[7];
    const float* dbh  = (const float*)d_in[8];
    const float* linW = (const float*)d_in[9];
    const float* linb = (const float*)d_in[10];
    float* out  = (float*)d_out;

    float* eWhT = (float*)d_ws;            // 512 x 1536 fp32 = 3 MB
    float* dWhT = eWhT + (size_t)G3 * HD;  // 3 MB

    dim3 tb(32, 8), tg(HD / 32, G3 / 32);
    transpose_tiled<<<tg, tb, 0, stream>>>(eWh, eWhT, G3, HD);
    transpose_tiled<<<tg, tb, 0, stream>>>(dWh, dWhT, G3, HD);

    gru_ae2<<<dim3(NB / 2), dim3(1024), 0, stream>>>(x, eWi, ebi, ebh, dWi, dbi, dbh,
                                                     linW, linb, eWhT, dWhT, out);
}